// Round 11
// baseline (335.008 us; speedup 1.0000x reference)
//
#include <hip/hip_runtime.h>
#include <hip/hip_bf16.h>

// Problem constants
#define BATCH 128
#define TSTEPS 64
#define EMB 256
#define HID 512
#define GATES 2048   // 4*HID
#define NFEAT 2048

typedef __bf16 bf16_t;
typedef __attribute__((ext_vector_type(8))) __bf16 bf16x8;
typedef __attribute__((ext_vector_type(4))) float f32x4;

#define MFMA16 __builtin_amdgcn_mfma_f32_16x16x32_bf16

// A/B fragment from row-major bf16: lane l -> row = row0 + (l&15), k = k0 + (l>>4)*8.
__device__ __forceinline__ bf16x8 frag16(const bf16_t* __restrict__ base, int row0, int stride,
                                         int k0, int lane) {
    return *(const bf16x8*)(base + (size_t)(row0 + (lane & 15)) * stride + k0 + ((lane >> 4) << 3));
}
// Same fragment from f32 source with inline convert (weights stay f32 in HBM).
__device__ __forceinline__ bf16x8 frag16f(const float* __restrict__ base, int row0, int stride,
                                          int k0, int lane) {
    const float* p = base + (size_t)(row0 + (lane & 15)) * stride + k0 + ((lane >> 4) << 3);
    float4 lo = *(const float4*)p;
    float4 hi = *(const float4*)(p + 4);
    bf16x8 v;
    v[0] = (bf16_t)lo.x; v[1] = (bf16_t)lo.y; v[2] = (bf16_t)lo.z; v[3] = (bf16_t)lo.w;
    v[4] = (bf16_t)hi.x; v[5] = (bf16_t)hi.y; v[6] = (bf16_t)hi.z; v[7] = (bf16_t)hi.w;
    return v;
}

__device__ __forceinline__ float sigm(float x) { return 1.f / (1.f + __expf(-x)); }
__device__ __forceinline__ float tanh_f(float x) { return 1.f - 2.f / (__expf(2.f * x) + 1.f); }

__device__ __forceinline__ float bflo(unsigned w) {
    return __builtin_bit_cast(float, (w & 0xffffu) << 16);
}
__device__ __forceinline__ float bfhi(unsigned w) {
    return __builtin_bit_cast(float, w & 0xffff0000u);
}
__device__ __forceinline__ unsigned f2bf(float x) {
    return (unsigned)__builtin_bit_cast(unsigned short, (bf16_t)x);
}

// LLC-coherent (sc0sc1) primitives — bypass L1/L2, never invalidate caches.
__device__ __forceinline__ unsigned ld_sys(const unsigned* p) {
    return __hip_atomic_load(p, __ATOMIC_RELAXED, __HIP_MEMORY_SCOPE_SYSTEM);
}
__device__ __forceinline__ void st_sys(unsigned* p, unsigned v) {
    __hip_atomic_store(p, v, __ATOMIC_RELAXED, __HIP_MEMORY_SCOPE_SYSTEM);
}
// Two 16B LLC loads in flight, one wait.
__device__ __forceinline__ void ld2_sys_v4(const void* p0, const void* p1, uint4& a, uint4& b) {
    asm volatile("global_load_dwordx4 %0, %2, off sc0 sc1\n\t"
                 "global_load_dwordx4 %1, %3, off sc0 sc1\n\t"
                 "s_waitcnt vmcnt(0)"
                 : "=&v"(a), "=&v"(b)
                 : "v"(p0), "v"(p1)
                 : "memory");
}

// ---------------- x_proj GEMM: inline gather + inline Wih cvt + inline bias + flag zero ------
// Block (bx=t, by): rows t*128..+128 of xproj, cols by*128..+128. 4 waves (2x2), 64x64/wave.
__global__ __launch_bounds__(256) void k_xproj(
    const int* __restrict__ m, const float* __restrict__ emb_tab,
    const float* __restrict__ Wih, const float* __restrict__ bih, const float* __restrict__ bhh,
    bf16_t* __restrict__ xproj, unsigned* __restrict__ flags) {
    if (blockIdx.x == 0 && blockIdx.y == 0) {
        st_sys(flags + threadIdx.x, 0u);
        st_sys(flags + 256 + threadIdx.x, 0u);
    }
    int lane = threadIdx.x & 63, w = threadIdx.x >> 6;
    int t = blockIdx.x;                  // 0..63
    int b0 = (w >> 1) * 64;
    int g0 = blockIdx.y * 128 + (w & 1) * 64;
    int q = lane >> 4;
    int tok[4];
    #pragma unroll
    for (int i = 0; i < 4; i++)
        tok[i] = m[(b0 + 16 * i + (lane & 15)) * TSTEPS + t];
    f32x4 acc[4][4] = {};
    #pragma unroll
    for (int k = 0; k < EMB; k += 32) {
        bf16x8 af[4], bf[4];
        #pragma unroll
        for (int i = 0; i < 4; i++) {
            const float* src = emb_tab + (size_t)tok[i] * EMB + k + q * 8;
            float4 lo = *(const float4*)(src);
            float4 hi = *(const float4*)(src + 4);
            bf16x8 v;
            v[0] = (bf16_t)lo.x; v[1] = (bf16_t)lo.y; v[2] = (bf16_t)lo.z; v[3] = (bf16_t)lo.w;
            v[4] = (bf16_t)hi.x; v[5] = (bf16_t)hi.y; v[6] = (bf16_t)hi.z; v[7] = (bf16_t)hi.w;
            af[i] = v;
        }
        #pragma unroll
        for (int j = 0; j < 4; j++) bf[j] = frag16f(Wih, g0 + 16 * j, EMB, k, lane);
        #pragma unroll
        for (int i = 0; i < 4; i++)
            #pragma unroll
            for (int j = 0; j < 4; j++)
                acc[i][j] = MFMA16(af[i], bf[j], acc[i][j], 0, 0, 0);
    }
    #pragma unroll
    for (int j = 0; j < 4; j++) {
        int g = g0 + 16 * j + (lane & 15);
        float bs = bih[g] + bhh[g];
        #pragma unroll
        for (int i = 0; i < 4; i++)
            #pragma unroll
            for (int r = 0; r < 4; r++) {
                int row = t * BATCH + b0 + 16 * i + (q << 2) + r;
                xproj[(size_t)row * GATES + g] = (bf16_t)(acc[i][j][r] + bs);
            }
    }
}

// ---------------- recurrence: 64 blocks = 8 batch-groups x 8 hidden-strips (R5 skeleton) -----
// 512 threads = 8 waves; wave w: gate g=w>>1, col-half hh=w&1 (32 j-cols = 2 MFMA tiles).
// Whh slice in registers (inline f32->bf16 cvt, pinned). h exchanged via LLC in fragment
// layout [parity][group][16 kt][64 lane][16B]; double-buffered by parity (skew<=1 induction).
// Per-wave plain-store flags (no RMW): wave drains own stores (vmcnt(0)), lane0 stores t+1.
// Wave 0 polls all 64 group-flags (one per lane, __all). t=0 shortcut: gates = xproj only.
__global__ __launch_bounds__(512, 1) void k_rnn(
    const bf16_t* __restrict__ xp,    // [8192][2048] bf16, row = t*128+b
    const float* __restrict__ whh,    // [2048][512] f32 (inline cvt at preload)
    char* __restrict__ hbuf,          // [2 parity][8 group][16KB frag image]
    unsigned* __restrict__ flags) {   // [8 group][8 strip][8 wave]
    __shared__ __align__(16) char hstage[16384];   // [16 kt][64 lane][16B]
    __shared__ float gex[4][16][66];               // gate exchange, padded
    const int tid = threadIdx.x;
    const int lane = tid & 63, w = tid >> 6;
    const int group = blockIdx.x >> 3;      // 0..7
    const int s     = blockIdx.x & 7;       // 0..7
    const int g = w >> 1, hh = w & 1;

    // --- preload Whh slice (f32 -> bf16) into registers and pin ---
    bf16x8 Bf0[16], Bf1[16];
    {
        const float* wb = whh + (size_t)(g * HID + s * 64 + hh * 32) * HID;
        #pragma unroll
        for (int kt = 0; kt < 16; ++kt) {
            Bf0[kt] = frag16f(wb, 0, HID, kt * 32, lane);
            Bf1[kt] = frag16f(wb, 16, HID, kt * 32, lane);
        }
        #pragma unroll
        for (int kt = 0; kt < 16; ++kt)
            asm volatile("" : "+v"(Bf0[kt]), "+v"(Bf1[kt]));
    }

    const int r_up = tid >> 5;              // 0..15 (batch row within group)
    const int c0 = (tid & 31) * 2;          // 0..62 (local col pair)
    float cst0 = 0.f, cst1 = 0.f;           // cell state

    // producer packet (one dword = 2 bf16) byte offset within a parity image
    size_t pk_off;
    {
        int j = s * 64 + c0;
        int kt = j >> 5;
        int lane_p = (((j & 31) >> 3) << 4) | r_up;
        pk_off = (size_t)group * 16384 + (size_t)(kt * 256 + lane_p * 4 + ((j & 7) >> 1)) * 4;
    }
    unsigned* myflag = flags + group * 64 + s * 8 + w;
    const unsigned* pollp = flags + group * 64 + lane;   // 64 lanes <-> 64 flags

    // ---------------- t = 0: h_0 = 0 -> gates = xproj only ----------------
    {
        const bf16_t* xrow = xp + ((size_t)(group * 16 + r_up)) * GATES + s * 64 + c0;
        unsigned xw0 = *(const unsigned*)(xrow);
        unsigned xw1 = *(const unsigned*)(xrow + HID);
        unsigned xw2 = *(const unsigned*)(xrow + 2 * HID);
        unsigned xw3 = *(const unsigned*)(xrow + 3 * HID);
        float iv0 = bflo(xw0), iv1 = bfhi(xw0);
        float fv0 = bflo(xw1), fv1 = bfhi(xw1);   // unused vs c0=0, kept for clarity
        float gv0 = bflo(xw2), gv1 = bfhi(xw2);
        float ov0 = bflo(xw3), ov1 = bfhi(xw3);
        (void)fv0; (void)fv1;
        cst0 = sigm(iv0) * tanh_f(gv0);           // c_0 = 0 -> f-gate term drops
        cst1 = sigm(iv1) * tanh_f(gv1);
        float h0v = sigm(ov0) * tanh_f(cst0);
        float h1v = sigm(ov1) * tanh_f(cst1);
        unsigned pack = f2bf(h0v) | (f2bf(h1v) << 16);
        st_sys((unsigned*)(hbuf + 131072 /*parity 1*/ + pk_off), pack);
        asm volatile("s_waitcnt vmcnt(0)" ::: "memory");
        if (lane == 0) st_sys(myflag, 1u);
    }

    // ---------------- t = 1..63 ----------------
    for (int t = 1; t < TSTEPS; ++t) {
        // xproj prefetch (regular cached loads; overlap the poll)
        const bf16_t* xrow = xp + ((size_t)(t * BATCH + group * 16 + r_up)) * GATES + s * 64 + c0;
        unsigned xw0 = *(const unsigned*)(xrow);
        unsigned xw1 = *(const unsigned*)(xrow + HID);
        unsigned xw2 = *(const unsigned*)(xrow + 2 * HID);
        unsigned xw3 = *(const unsigned*)(xrow + 3 * HID);

        if (w == 0) {   // wave-0-only poll: all 64 wave-flags of the group >= t
            unsigned v;
            do { v = ld_sys(pollp); } while (!__all((int)(v >= (unsigned)t)));
        }
        __syncthreads();   // B1: poll release
        asm volatile("" ::: "memory");

        // --- stage h_t: pure 16B copies LLC -> LDS (image already in fragment layout) ---
        {
            const char* src = hbuf + (size_t)(t & 1) * 131072 + (size_t)group * 16384;
            uint4 va, vb;
            ld2_sys_v4(src + (size_t)tid * 16, src + (size_t)(tid + 512) * 16, va, vb);
            *(uint4*)(hstage + (size_t)tid * 16) = va;
            *(uint4*)(hstage + (size_t)(tid + 512) * 16) = vb;
        }
        __syncthreads();   // B2: hstage ready

        // --- gates GEMM: 16 rows x 32 cols, K=512, B pinned in registers ---
        f32x4 a0 = {}, a1 = {};
        {
            const bf16_t* hs = (const bf16_t*)hstage;
            #pragma unroll
            for (int kt = 0; kt < 16; ++kt) {
                bf16x8 a = *(const bf16x8*)(hs + kt * 512 + lane * 8);   // lane-linear
                a0 = MFMA16(a, Bf0[kt], a0, 0, 0, 0);
                a1 = MFMA16(a, Bf1[kt], a1, 0, 0, 0);
            }
        }

        // --- gate exchange via LDS ---
        {
            const int jj = lane & 15, q = lane >> 4;
            #pragma unroll
            for (int rr = 0; rr < 4; ++rr) {
                gex[g][q * 4 + rr][hh * 32 + jj]      = a0[rr];
                gex[g][q * 4 + rr][hh * 32 + 16 + jj] = a1[rr];
            }
        }
        __syncthreads();   // B3: gex ready; hstage reusable next step

        // --- cell update (2 cells/thread) + packet store + per-wave flag ---
        {
            float2 gi = *(const float2*)&gex[0][r_up][c0];
            float2 gf = *(const float2*)&gex[1][r_up][c0];
            float2 gg = *(const float2*)&gex[2][r_up][c0];
            float2 go = *(const float2*)&gex[3][r_up][c0];
            float iv0 = gi.x + bflo(xw0), iv1 = gi.y + bfhi(xw0);
            float fv0 = gf.x + bflo(xw1), fv1 = gf.y + bfhi(xw1);
            float gv0 = gg.x + bflo(xw2), gv1 = gg.y + bfhi(xw2);
            float ov0 = go.x + bflo(xw3), ov1 = go.y + bfhi(xw3);
            cst0 = sigm(fv0) * cst0 + sigm(iv0) * tanh_f(gv0);
            cst1 = sigm(fv1) * cst1 + sigm(iv1) * tanh_f(gv1);
            float h0v = sigm(ov0) * tanh_f(cst0);
            float h1v = sigm(ov1) * tanh_f(cst1);
            unsigned pack = f2bf(h0v) | (f2bf(h1v) << 16);
            st_sys((unsigned*)(hbuf + (size_t)((t + 1) & 1) * 131072 + pk_off), pack);
            asm volatile("s_waitcnt vmcnt(0)" ::: "memory");   // wave's stores at LLC
            if (lane == 0) st_sys(myflag, (unsigned)(t + 1));
        }
    }
    // h_64 lives in parity (63+1)&1 = 0
}

// A-frag from the fragment image [group][16 kt][64 lane][8 bf16]
__device__ __forceinline__ bf16x8 frag_piece(const bf16_t* hb, int group, int kt, int lane) {
    return *(const bf16x8*)(hb + (size_t)group * 8192 + kt * 512 + lane * 8);
}

// ---------------- output GEMM: h[128,512] x Wout^T + b_out -> out f32 [128][2048] ------------
__global__ __launch_bounds__(256) void k_out(
    const bf16_t* __restrict__ h,      // hbuf parity 0 (h_64), fragment image
    const float* __restrict__ Wout,    // [2048][512] f32 (inline cvt)
    const float* __restrict__ bout,
    float* __restrict__ out) {
    int lane = threadIdx.x & 63, w = threadIdx.x >> 6;
    int r0 = blockIdx.x * 32 + (w & 1) * 16;
    int g0 = blockIdx.y * 128 + (w >> 1) * 64;
    int group = r0 >> 4;
    f32x4 acc[4] = {};
    #pragma unroll 4
    for (int kt = 0; kt < 16; ++kt) {
        bf16x8 a = frag_piece(h, group, kt, lane);
        #pragma unroll
        for (int t = 0; t < 4; t++) {
            bf16x8 b = frag16f(Wout, g0 + 16 * t, HID, kt * 32, lane);
            acc[t] = MFMA16(a, b, acc[t], 0, 0, 0);
        }
    }
    #pragma unroll
    for (int t = 0; t < 4; t++) {
        int g = g0 + 16 * t + (lane & 15);
        float bs = bout[g];
        #pragma unroll
        for (int r = 0; r < 4; r++) {
            int row = r0 + ((lane >> 4) << 2) + r;
            out[(size_t)row * NFEAT + g] = acc[t][r] + bs;
        }
    }
}

extern "C" void kernel_launch(void* const* d_in, const int* in_sizes, int n_in,
                              void* d_out, int out_size, void* d_ws, size_t ws_size,
                              hipStream_t stream) {
    const int*   m       = (const int*)d_in[0];
    // d_in[1] = images (unused by reference)
    const float* emb_tab = (const float*)d_in[2];
    const float* W_ih    = (const float*)d_in[3];
    const float* W_hh    = (const float*)d_in[4];
    const float* b_ih    = (const float*)d_in[5];
    const float* b_hh    = (const float*)d_in[6];
    const float* W_out   = (const float*)d_in[7];
    const float* b_out   = (const float*)d_in[8];

    char* ws = (char*)d_ws;
    bf16_t*   xpb   = (bf16_t*)  (ws + 0);          // 8192*2048*2 = 33554432
    char*     hbuf  = (char*)    (ws + 33554432);   // 2 parity x 131072 = 262144
    unsigned* flags = (unsigned*)(ws + 33816576);   // 512 dwords

    k_xproj<<<dim3(64, 16), dim3(256), 0, stream>>>(m, emb_tab, W_ih, b_ih, b_hh, xpb, flags);

    k_rnn<<<dim3(64), dim3(512), 0, stream>>>(xpb, W_hh, hbuf, flags);

    // h_64 in parity 0
    k_out<<<dim3(4, 16), dim3(256), 0, stream>>>((const bf16_t*)hbuf, W_out, b_out,
                                                 (float*)d_out);
}

// Round 12
// 271.032 us; speedup vs baseline: 1.2360x; 1.2360x over previous
//
#include <hip/hip_runtime.h>
#include <hip/hip_bf16.h>

// Problem constants
#define BATCH 128
#define TSTEPS 64
#define EMB 256
#define HID 512
#define GATES 2048   // 4*HID
#define NFEAT 2048

typedef __bf16 bf16_t;
typedef __attribute__((ext_vector_type(8))) __bf16 bf16x8;
typedef __attribute__((ext_vector_type(4))) float f32x4;

#define MFMA16 __builtin_amdgcn_mfma_f32_16x16x32_bf16

// A/B fragment from row-major bf16: lane l -> row = row0 + (l&15), k = k0 + (l>>4)*8.
__device__ __forceinline__ bf16x8 frag16(const bf16_t* __restrict__ base, int row0, int stride,
                                         int k0, int lane) {
    return *(const bf16x8*)(base + (size_t)(row0 + (lane & 15)) * stride + k0 + ((lane >> 4) << 3));
}
// Same fragment from f32 source with inline convert (weights stay f32 in HBM).
__device__ __forceinline__ bf16x8 frag16f(const float* __restrict__ base, int row0, int stride,
                                          int k0, int lane) {
    const float* p = base + (size_t)(row0 + (lane & 15)) * stride + k0 + ((lane >> 4) << 3);
    float4 lo = *(const float4*)p;
    float4 hi = *(const float4*)(p + 4);
    bf16x8 v;
    v[0] = (bf16_t)lo.x; v[1] = (bf16_t)lo.y; v[2] = (bf16_t)lo.z; v[3] = (bf16_t)lo.w;
    v[4] = (bf16_t)hi.x; v[5] = (bf16_t)hi.y; v[6] = (bf16_t)hi.z; v[7] = (bf16_t)hi.w;
    return v;
}

__device__ __forceinline__ float sigm(float x) { return 1.f / (1.f + __expf(-x)); }
__device__ __forceinline__ float tanh_f(float x) { return 1.f - 2.f / (__expf(2.f * x) + 1.f); }

__device__ __forceinline__ float bflo(unsigned w) {
    return __builtin_bit_cast(float, (w & 0xffffu) << 16);
}
__device__ __forceinline__ float bfhi(unsigned w) {
    return __builtin_bit_cast(float, w & 0xffff0000u);
}
__device__ __forceinline__ unsigned f2bf(float x) {
    return (unsigned)__builtin_bit_cast(unsigned short, (bf16_t)x);
}

// LLC-coherent (sc0sc1) primitives — bypass L1/L2, never invalidate caches.
__device__ __forceinline__ unsigned ld_sys(const unsigned* p) {
    return __hip_atomic_load(p, __ATOMIC_RELAXED, __HIP_MEMORY_SCOPE_SYSTEM);
}
__device__ __forceinline__ void st_sys(unsigned* p, unsigned v) {
    __hip_atomic_store(p, v, __ATOMIC_RELAXED, __HIP_MEMORY_SCOPE_SYSTEM);
}
// Two 16B LLC loads in flight, one wait.
__device__ __forceinline__ void ld2_sys_v4(const void* p0, const void* p1, uint4& a, uint4& b) {
    asm volatile("global_load_dwordx4 %0, %2, off sc0 sc1\n\t"
                 "global_load_dwordx4 %1, %3, off sc0 sc1\n\t"
                 "s_waitcnt vmcnt(0)"
                 : "=&v"(a), "=&v"(b)
                 : "v"(p0), "v"(p1)
                 : "memory");
}

// ---------------- mini-prep: emb gather (t-major, bf16) + biassum + cnt zero ----------------
// (Kernel-end L2 writeback makes plain stores visible to k_rnn's LLC-scope ops — proven R5.)
__global__ __launch_bounds__(256) void k_prep(
    const int* __restrict__ m, const float* __restrict__ emb_tab,
    const float* __restrict__ bih, const float* __restrict__ bhh,
    bf16_t* __restrict__ emb_b, float* __restrict__ biassum, unsigned* __restrict__ cnt) {
    const int NG = BATCH * TSTEPS * EMB / 4;   // gather in float4 quads = 524288
    const int N4 = GATES;                      // bias sum
    const int N5 = 256;                        // cnt dwords
    const long total = (long)NG + N4 + N5;
    for (long i = (long)blockIdx.x * blockDim.x + threadIdx.x; i < total;
         i += (long)gridDim.x * blockDim.x) {
        long x = i;
        if (x < NG) {
            int e4 = (int)(x & 63);            // quad index within row
            int rt = (int)(x >> 6);            // rt = t*128 + b  (t-major)
            int t = rt >> 7, b = rt & 127;
            int tok = m[b * TSTEPS + t];
            float4 v = *(const float4*)(emb_tab + (size_t)tok * EMB + e4 * 4);
            bf16_t* dst = emb_b + (size_t)rt * EMB + e4 * 4;
            dst[0] = (bf16_t)v.x; dst[1] = (bf16_t)v.y;
            dst[2] = (bf16_t)v.z; dst[3] = (bf16_t)v.w;
            continue;
        } x -= NG;
        if (x < N4) { biassum[x] = bih[x] + bhh[x]; continue; } x -= N4;
        cnt[x] = 0u;
    }
}

// ---------------- x_proj GEMM: emb_b bf16 x Wih^T (inline f32 cvt) -> xproj bf16 (+bias) -----
// 128x128 block tile, 4 waves (2x2), each wave 64x64 = 4x4 frags.
__global__ __launch_bounds__(256) void k_xproj(
    const bf16_t* __restrict__ A,     // emb_b [8192][256], row = t*128+b
    const float* __restrict__ Wih,    // [2048][256] f32
    const float* __restrict__ biassum,
    bf16_t* __restrict__ xproj) {     // [8192][2048] bf16
    int lane = threadIdx.x & 63, w = threadIdx.x >> 6;
    int r0 = blockIdx.x * 128 + (w >> 1) * 64;
    int g0 = blockIdx.y * 128 + (w & 1) * 64;
    f32x4 acc[4][4] = {};
    #pragma unroll
    for (int k = 0; k < EMB; k += 32) {
        bf16x8 af[4], bf[4];
        #pragma unroll
        for (int i = 0; i < 4; i++) af[i] = frag16(A, r0 + 16 * i, EMB, k, lane);
        #pragma unroll
        for (int j = 0; j < 4; j++) bf[j] = frag16f(Wih, g0 + 16 * j, EMB, k, lane);
        #pragma unroll
        for (int i = 0; i < 4; i++)
            #pragma unroll
            for (int j = 0; j < 4; j++)
                acc[i][j] = MFMA16(af[i], bf[j], acc[i][j], 0, 0, 0);
    }
    #pragma unroll
    for (int j = 0; j < 4; j++) {
        int g = g0 + 16 * j + (lane & 15);
        float bs = biassum[g];
        #pragma unroll
        for (int i = 0; i < 4; i++)
            #pragma unroll
            for (int r = 0; r < 4; r++) {
                int row = r0 + 16 * i + ((lane >> 4) << 2) + r;
                xproj[(size_t)row * GATES + g] = (bf16_t)(acc[i][j][r] + bs);
            }
    }
}

// ---------------- recurrence: 64 blocks = 8 batch-groups x 8 hidden-strips (R5 verbatim) -----
// 512 threads = 8 waves; wave w: gate g=w>>1, col-half hh=w&1 (32 cols = 2 MFMA tiles).
// Whh slice in registers (inline f32->bf16 cvt, pinned). h exchanged via LLC in MFMA-fragment
// layout [parity][group][16 kt][64 lane][16B]; staging is a pure 16B copy. Handshake = R5's
// proven protocol: post-store block barrier (drains all waves' stores) -> tid0 fetch_add ->
// consumer tid0 poll with s_sleep(1) (throttled; 64 pollers chip-wide). t=0 shortcut: h0=0.
__global__ __launch_bounds__(512, 1) void k_rnn(
    const bf16_t* __restrict__ xp,    // [8192][2048] bf16, row = t*128+b
    const float* __restrict__ whh,    // [2048][512] f32 (inline cvt at preload)
    char* __restrict__ hbuf,          // [2 parity][8 group][16KB frag image]
    unsigned* __restrict__ cnt) {     // [8 group][32 dwords] counters
    __shared__ __align__(16) char hstage[16384];   // [16 kt][64 lane][16B]
    __shared__ float gex[4][16][66];               // gate exchange, padded
    const int tid = threadIdx.x;
    const int lane = tid & 63, w = tid >> 6;
    const int group = blockIdx.x >> 3;      // 0..7
    const int s     = blockIdx.x & 7;       // 0..7
    const int g = w >> 1, hh = w & 1;

    // --- preload Whh slice (f32 -> bf16) into registers and pin ---
    bf16x8 Bf0[16], Bf1[16];
    {
        const float* wb = whh + (size_t)(g * HID + s * 64 + hh * 32) * HID;
        #pragma unroll
        for (int kt = 0; kt < 16; ++kt) {
            Bf0[kt] = frag16f(wb, 0, HID, kt * 32, lane);
            Bf1[kt] = frag16f(wb, 16, HID, kt * 32, lane);
        }
        #pragma unroll
        for (int kt = 0; kt < 16; ++kt)
            asm volatile("" : "+v"(Bf0[kt]), "+v"(Bf1[kt]));
    }

    const int r_up = tid >> 5;              // 0..15 (batch row within group)
    const int c0 = (tid & 31) * 2;          // 0..62 (local col pair)
    float cst0 = 0.f, cst1 = 0.f;           // cell state
    unsigned* myflag = cnt + group * 32;

    // h-store position (fragment layout), dword units; parity stride = 32768 dwords
    unsigned* hst;
    {
        int j = s * 64 + c0;
        int kt = j >> 5;
        int lane_p = (((j & 31) >> 3) << 4) | r_up;
        hst = (unsigned*)hbuf + (size_t)group * 4096 + kt * 256 + lane_p * 4 + ((j & 7) >> 1);
    }

    // ---------------- t = 0: h_0 = 0 -> gates = xproj only ----------------
    {
        const bf16_t* xrow = xp + ((size_t)(group * 16 + r_up)) * GATES + s * 64 + c0;
        unsigned xw0 = *(const unsigned*)(xrow);
        unsigned xw2 = *(const unsigned*)(xrow + 2 * HID);
        unsigned xw3 = *(const unsigned*)(xrow + 3 * HID);
        cst0 = sigm(bflo(xw0)) * tanh_f(bflo(xw2));    // c_0 = 0 -> f-gate term drops
        cst1 = sigm(bfhi(xw0)) * tanh_f(bfhi(xw2));
        float h0v = sigm(bflo(xw3)) * tanh_f(cst0);
        float h1v = sigm(bfhi(xw3)) * tanh_f(cst1);
        unsigned pack = f2bf(h0v) | (f2bf(h1v) << 16);
        st_sys(hst + 32768 /*parity 1*/, pack);
        __syncthreads();   // drains all waves' stores (implicit vmcnt(0))
        if (tid == 0)
            __hip_atomic_fetch_add(myflag, 1u, __ATOMIC_RELAXED, __HIP_MEMORY_SCOPE_SYSTEM);
    }

    // ---------------- t = 1..63 ----------------
    for (int t = 1; t < TSTEPS; ++t) {
        // xproj prefetch BEFORE the flag wait (independent of h; latency hides under wait)
        unsigned xw0, xw1, xw2, xw3;
        {
            const bf16_t* xrow = xp + ((size_t)(t * BATCH + group * 16 + r_up)) * GATES
                               + s * 64 + c0;
            xw0 = *(const unsigned*)(xrow);
            xw1 = *(const unsigned*)(xrow + HID);
            xw2 = *(const unsigned*)(xrow + 2 * HID);
            xw3 = *(const unsigned*)(xrow + 3 * HID);
        }

        // throttled single-dword poll (R5 protocol)
        if (tid == 0) {
            unsigned tgt = (unsigned)(8 * t);
            while (ld_sys(myflag) < tgt) __builtin_amdgcn_s_sleep(1);
        }
        __syncthreads();
        asm volatile("" ::: "memory");

        // --- stage h_t: pure 16B copy LLC -> LDS (already in fragment layout) ---
        {
            const char* gsrc = hbuf + (size_t)(t & 1) * 131072 + (size_t)group * 16384;
            uint4 va, vb;
            ld2_sys_v4(gsrc + (size_t)tid * 16, gsrc + (size_t)(tid + 512) * 16, va, vb);
            *(uint4*)(hstage + (size_t)tid * 16) = va;
            *(uint4*)(hstage + (size_t)(tid + 512) * 16) = vb;
        }
        __syncthreads();

        // --- gates GEMM: 16 rows x 32 cols, K=512, B pinned in registers ---
        f32x4 a0 = {}, a1 = {};
        {
            const bf16_t* hs = (const bf16_t*)hstage;
            #pragma unroll
            for (int kt = 0; kt < 16; ++kt) {
                bf16x8 a = *(const bf16x8*)(hs + kt * 512 + lane * 8);   // lane-linear
                a0 = MFMA16(a, Bf0[kt], a0, 0, 0, 0);
                a1 = MFMA16(a, Bf1[kt], a1, 0, 0, 0);
            }
        }

        // --- gate exchange via LDS ---
        {
            const int jj = lane & 15, q = lane >> 4;
            #pragma unroll
            for (int rr = 0; rr < 4; ++rr) {
                gex[g][q * 4 + rr][hh * 32 + jj]      = a0[rr];
                gex[g][q * 4 + rr][hh * 32 + 16 + jj] = a1[rr];
            }
        }
        __syncthreads();

        // --- cell update (2 cells/thread) + h frag-store to LLC ---
        {
            float2 gi = *(const float2*)&gex[0][r_up][c0];
            float2 gf = *(const float2*)&gex[1][r_up][c0];
            float2 gg = *(const float2*)&gex[2][r_up][c0];
            float2 go = *(const float2*)&gex[3][r_up][c0];
            float iv0 = gi.x + bflo(xw0), iv1 = gi.y + bfhi(xw0);
            float fv0 = gf.x + bflo(xw1), fv1 = gf.y + bfhi(xw1);
            float gv0 = gg.x + bflo(xw2), gv1 = gg.y + bfhi(xw2);
            float ov0 = go.x + bflo(xw3), ov1 = go.y + bfhi(xw3);
            cst0 = sigm(fv0) * cst0 + sigm(iv0) * tanh_f(gv0);
            cst1 = sigm(fv1) * cst1 + sigm(iv1) * tanh_f(gv1);
            float h0v = sigm(ov0) * tanh_f(cst0);
            float h1v = sigm(ov1) * tanh_f(cst1);
            unsigned pack = f2bf(h0v) | (f2bf(h1v) << 16);
            st_sys(hst + (size_t)(((t + 1) & 1)) * 32768, pack);
        }
        __syncthreads();   // drains all waves' stores before signal
        if (tid == 0 && t < TSTEPS - 1)
            __hip_atomic_fetch_add(myflag, 1u, __ATOMIC_RELAXED, __HIP_MEMORY_SCOPE_SYSTEM);
    }
    // h_64 lives in parity (63+1)&1 = 0
}

// A-frag from the fragment image [group][16 kt][64 lane][8 bf16]
__device__ __forceinline__ bf16x8 frag_piece(const bf16_t* hb, int group, int kt, int lane) {
    return *(const bf16x8*)(hb + (size_t)group * 8192 + kt * 512 + lane * 8);
}

// ---------------- output GEMM: h[128,512] x Wout^T + b_out -> out f32 [128][2048] ------------
__global__ __launch_bounds__(256) void k_out(
    const bf16_t* __restrict__ h,      // hbuf parity 0 (h_64), fragment image
    const float* __restrict__ Wout,    // [2048][512] f32 (inline cvt)
    const float* __restrict__ bout,
    float* __restrict__ out) {
    int lane = threadIdx.x & 63, w = threadIdx.x >> 6;
    int r0 = blockIdx.x * 32 + (w & 1) * 16;
    int g0 = blockIdx.y * 128 + (w >> 1) * 64;
    int group = r0 >> 4;
    f32x4 acc[4] = {};
    #pragma unroll 4
    for (int kt = 0; kt < 16; ++kt) {
        bf16x8 a = frag_piece(h, group, kt, lane);
        #pragma unroll
        for (int t = 0; t < 4; t++) {
            bf16x8 b = frag16f(Wout, g0 + 16 * t, HID, kt * 32, lane);
            acc[t] = MFMA16(a, b, acc[t], 0, 0, 0);
        }
    }
    #pragma unroll
    for (int t = 0; t < 4; t++) {
        int g = g0 + 16 * t + (lane & 15);
        float bs = bout[g];
        #pragma unroll
        for (int r = 0; r < 4; r++) {
            int row = r0 + ((lane >> 4) << 2) + r;
            out[(size_t)row * NFEAT + g] = acc[t][r] + bs;
        }
    }
}

extern "C" void kernel_launch(void* const* d_in, const int* in_sizes, int n_in,
                              void* d_out, int out_size, void* d_ws, size_t ws_size,
                              hipStream_t stream) {
    const int*   m       = (const int*)d_in[0];
    // d_in[1] = images (unused by reference)
    const float* emb_tab = (const float*)d_in[2];
    const float* W_ih    = (const float*)d_in[3];
    const float* W_hh    = (const float*)d_in[4];
    const float* b_ih    = (const float*)d_in[5];
    const float* b_hh    = (const float*)d_in[6];
    const float* W_out   = (const float*)d_in[7];
    const float* b_out   = (const float*)d_in[8];

    char* ws = (char*)d_ws;
    bf16_t*   xpb     = (bf16_t*)  (ws + 0);          // 8192*2048*2 = 33554432
    bf16_t*   emb_b   = (bf16_t*)  (ws + 33554432);   // 4194304
    char*     hbuf    = (char*)    (ws + 37748736);   // 2 parity x 131072 = 262144
    float*    biassum = (float*)   (ws + 38010880);   // 8192
    unsigned* cnt     = (unsigned*)(ws + 38019072);   // 1024

    k_prep<<<dim3(1024), dim3(256), 0, stream>>>(m, emb_tab, b_ih, b_hh, emb_b, biassum, cnt);

    k_xproj<<<dim3(64, 16), dim3(256), 0, stream>>>(emb_b, W_ih, biassum, xpb);

    k_rnn<<<dim3(64), dim3(512), 0, stream>>>(xpb, W_hh, hbuf, cnt);

    // h_64 in parity 0
    k_out<<<dim3(4, 16), dim3(256), 0, stream>>>((const bf16_t*)hbuf, W_out, b_out,
                                                 (float*)d_out);
}